// Round 2
// baseline (43.176 us; speedup 1.0000x reference)
//
#include <hip/hip_runtime.h>

#define EPS 1e-7f
#define NB 64
#define NI 1152
#define NJ 8
#define NK 43
#define NL 16
#define THREADS 384
#define CHUNKS 3   // NI / THREADS

__global__ __launch_bounds__(THREADS, 1)
void capsule_routing_kernel(const float* __restrict__ X, const float* __restrict__ W,
                            float* __restrict__ out) {
    __shared__ __align__(16) float sW[NJ*NK*NL];        // [j][k][l] = 5504
    __shared__ __align__(16) float xT[NJ][NI+4];        // x transposed [j][i]
    __shared__ __align__(16) float cT[NK][THREADS+4];   // softmax c for one chunk [k][i_local]
    __shared__ __align__(16) float sWv[NJ][44];         // accumulated Wv[j][k]
    __shared__ float sV[NK][NL];                        // current v
    __shared__ float sS[NK][NL];                        // s accumulator
    __shared__ float sG[NK*NJ];                         // G[k][j]
    __shared__ float sXs[NJ];
    __shared__ float sRed[NJ][48];

    const int tid = threadIdx.x;
    const int b = blockIdx.x;
    const float* Xb = X + (size_t)b * (NI*NJ);

    // ---- load W into LDS (float4) ----
    {
        const float4* W4 = (const float4*)W;
        float4* sW4 = (float4*)sW;
        for (int t = tid; t < (NJ*NK*NL)/4; t += THREADS) sW4[t] = W4[t];
    }
    // ---- load X transposed into LDS ----
    {
        const float4* X4 = (const float4*)Xb;
        for (int t = tid; t < (NI*NJ)/4; t += THREADS) {
            float4 v = X4[t];
            int i = t >> 1;
            int j0 = (t & 1) * 4;
            xT[j0+0][i] = v.x; xT[j0+1][i] = v.y; xT[j0+2][i] = v.z; xT[j0+3][i] = v.w;
        }
    }
    if (tid < NJ) sWv[tid][43] = 0.f;
    __syncthreads();

    // ---- xs[j] = sum_i x[i][j] ----
    {
        int j = tid / 48, sub = tid % 48;
        float p = 0.f;
        #pragma unroll
        for (int ii = 0; ii < NI/48; ++ii) p += xT[j][sub + 48*ii];
        sRed[j][sub] = p;
    }
    __syncthreads();
    if (tid < NJ) {
        float s = 0.f;
        for (int q = 0; q < 48; ++q) s += sRed[tid][q];
        sXs[tid] = s;
    }
    __syncthreads();
    // ---- s0 = (1/43) * xs . W  (uniform softmax at r=0) ----
    for (int t = tid; t < NK*NL; t += THREADS) {   // 688 elements > 384 threads!
        float s = 0.f;
        #pragma unroll
        for (int j = 0; j < NJ; ++j) s += sXs[j] * sW[j*NK*NL + t];
        sS[t >> 4][t & 15] = s * (1.0f/43.0f);
    }
    __syncthreads();
    // ---- squash -> v0 ----
    if (tid < NK) {
        float s2 = 0.f;
        #pragma unroll
        for (int l = 0; l < NL; ++l) { float v = sS[tid][l]; s2 += v*v; }
        float scale = s2 / ((1.f + s2) * sqrtf(s2 + EPS));
        #pragma unroll
        for (int l = 0; l < NL; ++l) sV[tid][l] = scale * sS[tid][l];
    }
    __syncthreads();
    // ---- Wv0[j,k] = sum_l W[j,k,l]*v0[k,l] ----
    if (tid < 352) {
        int j = tid / 44, k = tid % 44;
        if (k < NK) {
            float wv = 0.f;
            #pragma unroll
            for (int l = 0; l < NL; ++l) wv += sW[j*NK*NL + k*NL + l] * sV[k][l];
            sWv[j][k] = wv;
        }
    }
    __syncthreads();

    // ---- routing passes r=1, r=2 ----
    for (int pass = 0; pass < 2; ++pass) {
        float Greg = 0.f;   // this thread's G[k][j] partial (tid<344: k=tid>>3, j=tid&7)
        for (int chunk = 0; chunk < CHUNKS; ++chunk) {
            const int i = chunk*THREADS + tid;
            float xr[NJ];
            #pragma unroll
            for (int j = 0; j < NJ; ++j) xr[j] = xT[j][i];
            // logits a[k] = sum_j x[i,j] * WvAcc[j,k]  (WvAcc = Wv0 (+Wv1 in pass 2))
            float a[44];
            #pragma unroll
            for (int k = 0; k < 44; ++k) a[k] = 0.f;
            #pragma unroll
            for (int j = 0; j < NJ; ++j) {
                #pragma unroll
                for (int k4 = 0; k4 < 11; ++k4) {
                    float4 wv = *(const float4*)&sWv[j][k4*4];
                    a[k4*4+0] = fmaf(xr[j], wv.x, a[k4*4+0]);
                    a[k4*4+1] = fmaf(xr[j], wv.y, a[k4*4+1]);
                    a[k4*4+2] = fmaf(xr[j], wv.z, a[k4*4+2]);
                    a[k4*4+3] = fmaf(xr[j], wv.w, a[k4*4+3]);
                }
            }
            // in-thread softmax over k=0..42
            float m = a[0];
            #pragma unroll
            for (int k = 1; k < NK; ++k) m = fmaxf(m, a[k]);
            float Z = 0.f;
            #pragma unroll
            for (int k = 0; k < NK; ++k) { a[k] = __expf(a[k] - m); Z += a[k]; }
            float inv = 1.f / Z;
            __syncthreads();   // previous chunk's G-phase done reading cT
            #pragma unroll
            for (int k = 0; k < NK; ++k) cT[k][tid] = a[k] * inv;
            __syncthreads();   // cT ready
            // G-phase: G[k,j] += sum_{i in chunk} c[i,k]*x[i,j]
            if (tid < NK*NJ) {
                const int k = tid >> 3, j = tid & 7;
                const float4* cr = (const float4*)&cT[k][0];
                const float4* xrow = (const float4*)&xT[j][chunk*THREADS];
                #pragma unroll 4
                for (int q = 0; q < THREADS/4; ++q) {
                    float4 c4 = cr[q], x4 = xrow[q];
                    Greg = fmaf(c4.x, x4.x, Greg);
                    Greg = fmaf(c4.y, x4.y, Greg);
                    Greg = fmaf(c4.z, x4.z, Greg);
                    Greg = fmaf(c4.w, x4.w, Greg);
                }
            }
        }
        if (tid < NK*NJ) sG[tid] = Greg;
        __syncthreads();
        // s[k,l] = sum_j G[k,j] * W[j,k,l]   (688 elements > 384 threads -> strided)
        for (int t = tid; t < NK*NL; t += THREADS) {
            const int k = t >> 4;
            float s = 0.f;
            #pragma unroll
            for (int j = 0; j < NJ; ++j) s = fmaf(sG[k*8+j], sW[j*NK*NL + t], s);
            sS[k][t & 15] = s;
        }
        __syncthreads();
        // squash -> v
        if (tid < NK) {
            float s2 = 0.f;
            #pragma unroll
            for (int l = 0; l < NL; ++l) { float v = sS[tid][l]; s2 += v*v; }
            float scale = s2 / ((1.f + s2) * sqrtf(s2 + EPS));
            #pragma unroll
            for (int l = 0; l < NL; ++l) sV[tid][l] = scale * sS[tid][l];
        }
        __syncthreads();
        if (pass == 0) {
            // accumulate Wv: logits for pass 2 are x.(Wv0+Wv1)
            if (tid < 352) {
                int j = tid / 44, k = tid % 44;
                if (k < NK) {
                    float wv = 0.f;
                    #pragma unroll
                    for (int l = 0; l < NL; ++l) wv += sW[j*NK*NL + k*NL + l] * sV[k][l];
                    sWv[j][k] += wv;
                }
            }
        } else {
            // final output v2 -> d_out[b,k,l]
            for (int t = tid; t < NK*NL; t += THREADS)
                out[(size_t)b*NK*NL + t] = sV[t >> 4][t & 15];
        }
        __syncthreads();
    }
}

extern "C" void kernel_launch(void* const* d_in, const int* in_sizes, int n_in,
                              void* d_out, int out_size, void* d_ws, size_t ws_size,
                              hipStream_t stream) {
    const float* X = (const float*)d_in[0];   // [64,1152,8]
    const float* W = (const float*)d_in[1];   // [8,43,16]
    float* out = (float*)d_out;               // [64,43,16]
    hipLaunchKernelGGL(capsule_routing_kernel, dim3(NB), dim3(THREADS), 0, stream,
                       X, W, out);
}

// Round 3
// 36.028 us; speedup vs baseline: 1.1984x; 1.1984x over previous
//
#include <hip/hip_runtime.h>

#define EPS 1e-7f
#define NB 64
#define NI 1152
#define NJ 8
#define NK 43
#define NL 16
#define THREADS 384
#define CHUNKS 3          // NI / THREADS
#define NKG 11            // groups of 4 k's (44 = NK+1 pad)
#define GS 16             // i-slices in G phase
#define GTHREADS (NKG*GS) // 176
#define GITER (THREADS/GS)// 24 i's per G-thread per chunk
#define CPSTRIDE 387      // float4 row stride for cP (384 + 3 pad)
#define GPSTRIDE 34       // float row stride for Gp (32 + 2 pad)

__global__ __launch_bounds__(THREADS, 1)
void capsule_routing_kernel(const float* __restrict__ X, const float* __restrict__ W,
                            float* __restrict__ out) {
    __shared__ __align__(16) float  sW[NJ*NK*NL];          // 22,016 B
    __shared__ __align__(16) float  xR[NI*8];              // 36,864 B  (i-major, native layout)
    __shared__ __align__(16) float4 cP[NKG*CPSTRIDE];      // 68,112 B  (packed c, per chunk)
    __shared__ __align__(16) float  Gp[GTHREADS*GPSTRIDE]; // 23,936 B  (G partials; aliased as prologue scratch)
    __shared__ __align__(16) float  sWv[NJ][44];           //  1,408 B
    __shared__ float sV[NK][NL];                           //  2,752 B
    __shared__ float sS[NK][NL];                           //  2,752 B
    __shared__ float sG[NK*NJ];                            //  1,376 B
    __shared__ float sXs[NJ];

    const int tid = threadIdx.x;
    const int b = blockIdx.x;
    const float* Xb = X + (size_t)b * (NI*NJ);
    float4* xR4 = (float4*)xR;

    // ---- load W into LDS ----
    {
        const float4* W4 = (const float4*)W;
        float4* sW4 = (float4*)sW;
        for (int t = tid; t < (NJ*NK*NL)/4; t += THREADS) sW4[t] = W4[t];
    }
    // ---- load X into LDS, native i-major layout ----
    {
        const float4* X4 = (const float4*)Xb;
        #pragma unroll
        for (int r = 0; r < 6; ++r) xR4[tid + r*THREADS] = X4[tid + r*THREADS];
    }
    __syncthreads();

    // ---- xs[j] = sum_i x[i][j]  (scratch aliased onto Gp) ----
    {
        const int j = tid / 48, sub = tid % 48;
        float p = 0.f;
        #pragma unroll
        for (int ii = 0; ii < NI/48; ++ii) p += xR[(sub + 48*ii)*8 + j];
        Gp[j*48 + sub] = p;
    }
    __syncthreads();
    if (tid < NJ) {
        float s = 0.f;
        for (int q = 0; q < 48; ++q) s += Gp[tid*48 + q];
        sXs[tid] = s;
    }
    __syncthreads();
    // ---- s0 = (1/43) * xs . W ----
    for (int t = tid; t < NK*NL; t += THREADS) {
        float s = 0.f;
        #pragma unroll
        for (int j = 0; j < NJ; ++j) s += sXs[j] * sW[j*NK*NL + t];
        sS[t >> 4][t & 15] = s * (1.0f/43.0f);
    }
    __syncthreads();
    // ---- squash -> v0 ----
    if (tid < NK) {
        float s2 = 0.f;
        #pragma unroll
        for (int l = 0; l < NL; ++l) { float v = sS[tid][l]; s2 += v*v; }
        float scale = s2 / ((1.f + s2) * sqrtf(s2 + EPS));
        #pragma unroll
        for (int l = 0; l < NL; ++l) sV[tid][l] = scale * sS[tid][l];
    }
    if (tid < NJ) sWv[tid][43] = 0.f;
    __syncthreads();
    // ---- Wv0[j,k] = sum_l W[j,k,l]*v0[k,l] ----
    if (tid < 352) {
        const int j = tid / 44, k = tid % 44;
        if (k < NK) {
            float wv = 0.f;
            #pragma unroll
            for (int l = 0; l < NL; ++l) wv += sW[j*NK*NL + k*NL + l] * sV[k][l];
            sWv[j][k] = wv;
        }
    }
    __syncthreads();

    // ---- routing passes r=1, r=2 ----
    for (int pass = 0; pass < 2; ++pass) {
        float acc[4][8];
        #pragma unroll
        for (int q = 0; q < 4; ++q)
            #pragma unroll
            for (int j = 0; j < 8; ++j) acc[q][j] = 0.f;

        for (int chunk = 0; chunk < CHUNKS; ++chunk) {
            const int i = chunk*THREADS + tid;
            // ---- Phase A: logits + softmax for own i ----
            float4 x0 = xR4[i*2], x1 = xR4[i*2 + 1];
            float xr[NJ] = {x0.x, x0.y, x0.z, x0.w, x1.x, x1.y, x1.z, x1.w};
            float a[44];
            #pragma unroll
            for (int k = 0; k < 44; ++k) a[k] = 0.f;
            #pragma unroll
            for (int j = 0; j < NJ; ++j) {
                #pragma unroll
                for (int k4 = 0; k4 < 11; ++k4) {
                    float4 wv = *(const float4*)&sWv[j][k4*4];
                    a[k4*4+0] = fmaf(xr[j], wv.x, a[k4*4+0]);
                    a[k4*4+1] = fmaf(xr[j], wv.y, a[k4*4+1]);
                    a[k4*4+2] = fmaf(xr[j], wv.z, a[k4*4+2]);
                    a[k4*4+3] = fmaf(xr[j], wv.w, a[k4*4+3]);
                }
            }
            float m = a[0];
            #pragma unroll
            for (int k = 1; k < NK; ++k) m = fmaxf(m, a[k]);
            float Z = 0.f;
            #pragma unroll
            for (int k = 0; k < NK; ++k) { a[k] = __expf(a[k] - m); Z += a[k]; }
            float inv = 1.f / Z;
            #pragma unroll
            for (int k = 0; k < NK; ++k) a[k] *= inv;
            a[43] = 0.f;
            __syncthreads();   // previous chunk's Phase B done reading cP
            #pragma unroll
            for (int kg = 0; kg < NKG; ++kg)
                cP[kg*CPSTRIDE + tid] = make_float4(a[4*kg], a[4*kg+1], a[4*kg+2], a[4*kg+3]);
            __syncthreads();   // cP ready
            // ---- Phase B: register-blocked G accumulate ----
            if (tid < GTHREADS) {
                const int kg = tid >> 4, s = tid & 15;
                #pragma unroll 4
                for (int ii = 0; ii < GITER; ++ii) {
                    const int il = s + GS*ii;           // interleaved slice
                    float4 c4 = cP[kg*CPSTRIDE + il];
                    const int gi = chunk*THREADS + il;
                    float4 xa = xR4[gi*2], xb = xR4[gi*2 + 1];
                    acc[0][0]=fmaf(c4.x,xa.x,acc[0][0]); acc[0][1]=fmaf(c4.x,xa.y,acc[0][1]);
                    acc[0][2]=fmaf(c4.x,xa.z,acc[0][2]); acc[0][3]=fmaf(c4.x,xa.w,acc[0][3]);
                    acc[0][4]=fmaf(c4.x,xb.x,acc[0][4]); acc[0][5]=fmaf(c4.x,xb.y,acc[0][5]);
                    acc[0][6]=fmaf(c4.x,xb.z,acc[0][6]); acc[0][7]=fmaf(c4.x,xb.w,acc[0][7]);
                    acc[1][0]=fmaf(c4.y,xa.x,acc[1][0]); acc[1][1]=fmaf(c4.y,xa.y,acc[1][1]);
                    acc[1][2]=fmaf(c4.y,xa.z,acc[1][2]); acc[1][3]=fmaf(c4.y,xa.w,acc[1][3]);
                    acc[1][4]=fmaf(c4.y,xb.x,acc[1][4]); acc[1][5]=fmaf(c4.y,xb.y,acc[1][5]);
                    acc[1][6]=fmaf(c4.y,xb.z,acc[1][6]); acc[1][7]=fmaf(c4.y,xb.w,acc[1][7]);
                    acc[2][0]=fmaf(c4.z,xa.x,acc[2][0]); acc[2][1]=fmaf(c4.z,xa.y,acc[2][1]);
                    acc[2][2]=fmaf(c4.z,xa.z,acc[2][2]); acc[2][3]=fmaf(c4.z,xa.w,acc[2][3]);
                    acc[2][4]=fmaf(c4.z,xb.x,acc[2][4]); acc[2][5]=fmaf(c4.z,xb.y,acc[2][5]);
                    acc[2][6]=fmaf(c4.z,xb.z,acc[2][6]); acc[2][7]=fmaf(c4.z,xb.w,acc[2][7]);
                    acc[3][0]=fmaf(c4.w,xa.x,acc[3][0]); acc[3][1]=fmaf(c4.w,xa.y,acc[3][1]);
                    acc[3][2]=fmaf(c4.w,xa.z,acc[3][2]); acc[3][3]=fmaf(c4.w,xa.w,acc[3][3]);
                    acc[3][4]=fmaf(c4.w,xb.x,acc[3][4]); acc[3][5]=fmaf(c4.w,xb.y,acc[3][5]);
                    acc[3][6]=fmaf(c4.w,xb.z,acc[3][6]); acc[3][7]=fmaf(c4.w,xb.w,acc[3][7]);
                }
            }
        }
        // ---- write G partials (float2, stride-34 rows -> 2-way banks) ----
        if (tid < GTHREADS) {
            #pragma unroll
            for (int q = 0; q < 4; ++q)
                #pragma unroll
                for (int jh = 0; jh < 4; ++jh)
                    *(float2*)&Gp[tid*GPSTRIDE + q*8 + jh*2] =
                        make_float2(acc[q][jh*2], acc[q][jh*2+1]);
        }
        __syncthreads();
        // ---- reduce over slices -> sG[k*8+j] ----
        if (tid < NK*NJ) {
            const int k = tid >> 3, j = tid & 7;
            const int kg = k >> 2, k4 = k & 3;
            float g = 0.f;
            #pragma unroll
            for (int s = 0; s < GS; ++s) g += Gp[(kg*GS + s)*GPSTRIDE + k4*8 + j];
            sG[tid] = g;
        }
        __syncthreads();
        // ---- s[k,l] = sum_j G[k,j] * W[j,k,l] ----
        for (int t = tid; t < NK*NL; t += THREADS) {
            const int k = t >> 4;
            float s = 0.f;
            #pragma unroll
            for (int j = 0; j < NJ; ++j) s = fmaf(sG[k*8+j], sW[j*NK*NL + t], s);
            sS[k][t & 15] = s;
        }
        __syncthreads();
        // ---- squash -> v ----
        if (tid < NK) {
            float s2 = 0.f;
            #pragma unroll
            for (int l = 0; l < NL; ++l) { float v = sS[tid][l]; s2 += v*v; }
            float scale = s2 / ((1.f + s2) * sqrtf(s2 + EPS));
            #pragma unroll
            for (int l = 0; l < NL; ++l) sV[tid][l] = scale * sS[tid][l];
        }
        __syncthreads();
        if (pass == 0) {
            if (tid < 352) {
                const int j = tid / 44, k = tid % 44;
                if (k < NK) {
                    float wv = 0.f;
                    #pragma unroll
                    for (int l = 0; l < NL; ++l) wv += sW[j*NK*NL + k*NL + l] * sV[k][l];
                    sWv[j][k] += wv;
                }
            }
        } else {
            for (int t = tid; t < NK*NL; t += THREADS)
                out[(size_t)b*NK*NL + t] = sV[t >> 4][t & 15];
        }
        __syncthreads();
    }
}

extern "C" void kernel_launch(void* const* d_in, const int* in_sizes, int n_in,
                              void* d_out, int out_size, void* d_ws, size_t ws_size,
                              hipStream_t stream) {
    const float* X = (const float*)d_in[0];   // [64,1152,8]
    const float* W = (const float*)d_in[1];   // [8,43,16]
    float* out = (float*)d_out;               // [64,43,16]
    hipLaunchKernelGGL(capsule_routing_kernel, dim3(NB), dim3(THREADS), 0, stream,
                       X, W, out);
}